// Round 2
// baseline (764.519 us; speedup 1.0000x reference)
//
#include <hip/hip_runtime.h>

// ---------------- types / helpers ----------------
typedef __attribute__((ext_vector_type(4))) float f32x4;
typedef __attribute__((ext_vector_type(8))) short s16x8;

#define MFMA16(a, b, c) __builtin_amdgcn_mfma_f32_16x16x32_bf16(a, b, c, 0, 0, 0)

static __device__ __forceinline__ unsigned short f2b(float f) {
  unsigned int u = __float_as_uint(f);
  u += 0x7fff + ((u >> 16) & 1);   // round-to-nearest-even
  return (unsigned short)(u >> 16);
}

static __device__ __forceinline__ void gload_lds16(const unsigned short* g, unsigned short* l) {
  __builtin_amdgcn_global_load_lds(
      (const __attribute__((address_space(1))) unsigned int*)g,
      (__attribute__((address_space(3))) unsigned int*)l, 16, 0, 0);
}

// ---------------- problem constants ----------------
#define BW    2048
#define NTOK  49
#define CDIM  384
#define NHEAD 12
#define HDIM  32
#define NWIN  64
#define MROWS (BW * NTOK)        // 100352
#define SCALE 0.17677669529663687f  // 32^-0.5
#define QK_ELEMS ((size_t)BW * NHEAD * NTOK * HDIM)   // 38,535,168 per Q / K

// workspace byte offsets (total 239,766,528 B — under the round-1-proven 316.8 MB)
#define OFF_X    ((size_t)0)                 // x bf16, later reused as attn_out bf16 (77,070,336)
#define OFF_Q    ((size_t)77070336)          // Q [b][h][49][32] bf16 (77,070,336)
#define OFF_K    ((size_t)154140672)         // K [b][h][49][32] bf16 (77,070,336)
#define OFF_QW   ((size_t)231211008)         // qkv_w bf16 (884,736)
#define OFF_PW   ((size_t)232095744)         // proj_w bf16 (294,912)
#define OFF_COMB ((size_t)232390656)         // comb f32 (7,375,872)
// V^T [b][h][32][64] bf16 (100,663,296 B) lives in d_out (154 MB fp32, dead until proj GEMM).
// Pad tokens 49..63 are never written: P columns >=49 are exactly 0, and harness poison
// 0xAA is a finite bf16, so 0 * garbage = 0.

// ---------------- cast fp32 -> bf16 (x4 vectorized) ----------------
__global__ __launch_bounds__(256) void cast_kernel(const float* __restrict__ src,
                                                   unsigned short* __restrict__ dst, int n4) {
  int i = blockIdx.x * 256 + threadIdx.x;
  if (i >= n4) return;
  float4 f = ((const float4*)src)[i];
  ushort4 o;
  o.x = f2b(f.x); o.y = f2b(f.y); o.z = f2b(f.z); o.w = f2b(f.w);
  ((ushort4*)dst)[i] = o;
}

// ---------------- comb[w][h][i*49+j] = mask[w][ij] + bias_table[rel(i,j)][h] ----------------
__global__ __launch_bounds__(256) void build_comb(const float* __restrict__ mask,
                                                  const float* __restrict__ bias_table,
                                                  float* __restrict__ comb) {
  int idx = blockIdx.x * 256 + threadIdx.x;
  if (idx >= NWIN * NHEAD * NTOK * NTOK) return;
  int ij = idx % (NTOK * NTOK);
  int wh = idx / (NTOK * NTOK);
  int h = wh % NHEAD;
  int w = wh / NHEAD;
  int i = ij / NTOK, j = ij % NTOK;
  int yi = i / 7, xi = i % 7, yj = j / 7, xj = j % 7;
  int rel = (yi - yj + 6) * 13 + (xi - xj + 6);
  comb[idx] = mask[w * (NTOK * NTOK) + ij] + bias_table[rel * NHEAD + h];
}

// ---------------- m97-style GEMM: C = A[M,K] * Bt[N,K]^T + bias ----------------
// 128x128 tile, BK=32, 256 threads (4 waves, each 64x64), 16x16x32 bf16 MFMA.
// MODE 0: plain fp32 C[M,N].  MODE 2: qkv scatter — Q/K -> [b][h][49][32] bf16,
// V -> V^T [b][h][32][64] bf16 (which = blockIdx.x/3 is block-uniform since N=1152=9*128).
template <int MODE>
__global__ __launch_bounds__(256) void gemm_bt(const unsigned short* __restrict__ A,
                                               const unsigned short* __restrict__ Bt,
                                               const float* __restrict__ bias,
                                               void* __restrict__ Cv,
                                               unsigned short* __restrict__ vtb,
                                               int M, int N, int K) {
  __shared__ __align__(16) unsigned short As[128 * 32];
  __shared__ __align__(16) unsigned short Bs[128 * 32];
  const int tid = threadIdx.x;
  const int lane = tid & 63;
  const int wave = tid >> 6;
  const int lr = lane & 15, lg = lane >> 4;
  const int wm = (wave >> 1) * 64, wn = (wave & 1) * 64;
  const size_t tileM = (size_t)blockIdx.y * 128;
  const size_t tileN = (size_t)blockIdx.x * 128;

  const unsigned short* Ab = A + tileM * K;
  const unsigned short* Bb = Bt + tileN * K;

  // staging: chunk c covers 8 bf16; row = c>>2, kcol = (c&3)*8; LDS dst = c*16B (lane-contiguous)
  const int c0 = tid, c1 = tid + 256;
  const size_t a0 = (size_t)(c0 >> 2) * K + (c0 & 3) * 8;
  const size_t a1 = (size_t)(c1 >> 2) * K + (c1 & 3) * 8;

  f32x4 acc[4][4] = {};

  for (int k0 = 0; k0 < K; k0 += 32) {
    gload_lds16(Ab + a0 + k0, As + c0 * 8);
    gload_lds16(Ab + a1 + k0, As + c1 * 8);
    gload_lds16(Bb + a0 + k0, Bs + c0 * 8);
    gload_lds16(Bb + a1 + k0, Bs + c1 * 8);
    __syncthreads();
    s16x8 af[4], bf[4];
#pragma unroll
    for (int mt = 0; mt < 4; ++mt)
      af[mt] = *(const s16x8*)&As[(wm + mt * 16 + lr) * 32 + lg * 8];
#pragma unroll
    for (int nt = 0; nt < 4; ++nt)
      bf[nt] = *(const s16x8*)&Bs[(wn + nt * 16 + lr) * 32 + lg * 8];
#pragma unroll
    for (int mt = 0; mt < 4; ++mt)
#pragma unroll
      for (int nt = 0; nt < 4; ++nt)
        acc[mt][nt] = MFMA16(af[mt], bf[nt], acc[mt][nt]);
    __syncthreads();
  }

  if (MODE == 0) {
    float* Cf = (float*)Cv;
#pragma unroll
    for (int nt = 0; nt < 4; ++nt) {
      const size_t gcol = tileN + wn + nt * 16 + lr;
      const float bv = bias[gcol];
#pragma unroll
      for (int mt = 0; mt < 4; ++mt)
#pragma unroll
        for (int r = 0; r < 4; ++r) {
          const size_t grow = tileM + wm + mt * 16 + lg * 4 + r;  // C/D: row=(lane>>4)*4+r, col=lane&15
          Cf[grow * (size_t)N + gcol] = acc[mt][nt][r] + bv;
        }
    }
  } else {
    unsigned short* qko = (unsigned short*)Cv;   // Q region base; K at +QK_ELEMS
    const int which = blockIdx.x / 3;            // 0=Q 1=K 2=V (block-uniform)
#pragma unroll
    for (int mt = 0; mt < 4; ++mt)
#pragma unroll
      for (int r = 0; r < 4; ++r) {
        const int grow = (int)tileM + wm + mt * 16 + lg * 4 + r;
        const int b = grow / 49;
        const int t = grow - b * 49;
#pragma unroll
        for (int nt = 0; nt < 4; ++nt) {
          const int gcol = (int)tileN + wn + nt * 16 + lr;
          const int cc = gcol - which * 384;
          const int hh = cc >> 5, d = cc & 31;
          const float v = acc[mt][nt][r] + bias[gcol];
          const size_t bh = (size_t)b * NHEAD + hh;
          if (which == 2) vtb[(bh * HDIM + d) * 64 + t] = f2b(v);
          else            qko[(size_t)which * QK_ELEMS + (bh * NTOK + t) * HDIM + d] = f2b(v);
        }
      }
  }
}

// ---------------- attention: one wave per (window b, head h) ----------------
// q,k: [b][h][49][32] bf16 ; vt: [b][h][32][64] bf16 ; comb: [64][12][49*49] f32
// out: [BW*49, 384] bf16. LDS: Pt only (9216 B) -> ~16 waves/CU.
#define PSTR 72   // Pt row stride (elems): 144 B rows, 16B-aligned
__global__ __launch_bounds__(64) void attn_kernel(const unsigned short* __restrict__ q,
                                                  const unsigned short* __restrict__ k,
                                                  const unsigned short* __restrict__ vt,
                                                  const float* __restrict__ comb,
                                                  unsigned short* __restrict__ out) {
  __shared__ __align__(16) unsigned short Pt[64 * PSTR];
  const int b = blockIdx.x;
  const int h = blockIdx.y;
  const int lane = threadIdx.x;
  const int lr = lane & 15, lg = lane >> 4;
  const size_t bh = (size_t)b * NHEAD + h;
  const unsigned short* qb = q + bh * (NTOK * HDIM);
  const unsigned short* kb = k + bh * (NTOK * HDIM);
  const unsigned short* vb = vt + bh * (HDIM * 64);

  // Q,K fragments, fully coalesced (16 B/lane, 1024 B/wave contiguous).
  // Rows t>=49 read the next (b,h) tile — finite garbage, feeds only discarded
  // S rows (rowok=false) / S cols (col>=49 forced to -1e30).
  s16x8 qf[4], kf[4];
#pragma unroll
  for (int mt = 0; mt < 4; ++mt) {
    const int off = (mt * 16 + lr) * HDIM + lg * 8;
    qf[mt] = *(const s16x8*)(qb + off);
    kf[mt] = *(const s16x8*)(kb + off);
  }

  f32x4 S[4][4] = {};
#pragma unroll
  for (int mt = 0; mt < 4; ++mt)
#pragma unroll
    for (int nt = 0; nt < 4; ++nt)
      S[mt][nt] = MFMA16(qf[mt], kf[nt], S[mt][nt]);

  const float* cb = comb + ((size_t)(b & 63) * NHEAD + h) * (NTOK * NTOK);

  // masked softmax per row; a row lives across 16 lanes sharing lg, 4 regs (nt)
#pragma unroll
  for (int mt = 0; mt < 4; ++mt) {
#pragma unroll
    for (int r = 0; r < 4; ++r) {
      const int row = mt * 16 + lg * 4 + r;
      const bool rowok = row < NTOK;
      float sv[4];
      float mx = -1e30f;
#pragma unroll
      for (int nt = 0; nt < 4; ++nt) {
        const int col = nt * 16 + lr;
        float s;
        if (col < NTOK)
          s = rowok ? S[mt][nt][r] * SCALE + cb[row * NTOK + col] : 0.0f;
        else
          s = -1e30f;
        sv[nt] = s;
        mx = fmaxf(mx, s);
      }
#pragma unroll
      for (int off = 8; off; off >>= 1) mx = fmaxf(mx, __shfl_xor(mx, off, 16));
      float sum = 0.f;
#pragma unroll
      for (int nt = 0; nt < 4; ++nt) {
        float e = exp2f((sv[nt] - mx) * 1.4426950408889634f);  // col>=49 -> exp2(-inf) = 0 exactly
        sv[nt] = e;
        sum += e;
      }
#pragma unroll
      for (int off = 8; off; off >>= 1) sum += __shfl_xor(sum, off, 16);
      const float inv = 1.0f / sum;
#pragma unroll
      for (int nt = 0; nt < 4; ++nt)
        Pt[row * PSTR + nt * 16 + lr] = f2b(sv[nt] * inv);
    }
  }
  __syncthreads();

  // O = P(64x64, cols>=49 are 0) * V^T-frags from global (pad cols multiply by 0)
  f32x4 O[4][2] = {};
#pragma unroll
  for (int ks = 0; ks < 2; ++ks) {
    s16x8 pf[4], vf[2];
#pragma unroll
    for (int mt = 0; mt < 4; ++mt)
      pf[mt] = *(const s16x8*)&Pt[(mt * 16 + lr) * PSTR + ks * 32 + lg * 8];
#pragma unroll
    for (int n2 = 0; n2 < 2; ++n2)
      vf[n2] = *(const s16x8*)(vb + (n2 * 16 + lr) * 64 + ks * 32 + lg * 8);
#pragma unroll
    for (int mt = 0; mt < 4; ++mt)
#pragma unroll
      for (int n2 = 0; n2 < 2; ++n2)
        O[mt][n2] = MFMA16(pf[mt], vf[n2], O[mt][n2]);
  }

  unsigned short* ob = out + (size_t)b * NTOK * CDIM + h * HDIM;
#pragma unroll
  for (int mt = 0; mt < 4; ++mt)
#pragma unroll
    for (int r = 0; r < 4; ++r) {
      const int row = mt * 16 + lg * 4 + r;
      if (row < NTOK) {
#pragma unroll
        for (int n2 = 0; n2 < 2; ++n2)
          ob[(size_t)row * CDIM + n2 * 16 + lr] = f2b(O[mt][n2][r]);
      }
    }
}

// ---------------- launch ----------------
extern "C" void kernel_launch(void* const* d_in, const int* in_sizes, int n_in,
                              void* d_out, int out_size, void* d_ws, size_t ws_size,
                              hipStream_t stream) {
  const float* x          = (const float*)d_in[0];
  const float* mask       = (const float*)d_in[1];
  const float* qkv_w      = (const float*)d_in[2];
  const float* qkv_b      = (const float*)d_in[3];
  const float* proj_w     = (const float*)d_in[4];
  const float* proj_b     = (const float*)d_in[5];
  const float* bias_table = (const float*)d_in[6];
  float* out = (float*)d_out;
  char* ws = (char*)d_ws;

  unsigned short* xb   = (unsigned short*)(ws + OFF_X);    // x bf16, later attn_out
  unsigned short* qb   = (unsigned short*)(ws + OFF_Q);
  unsigned short* kb   = (unsigned short*)(ws + OFF_K);
  unsigned short* qw   = (unsigned short*)(ws + OFF_QW);
  unsigned short* pw   = (unsigned short*)(ws + OFF_PW);
  float* comb          = (float*)(ws + OFF_COMB);
  unsigned short* vtb  = (unsigned short*)d_out;           // V^T scratch in d_out (dead until proj)

  // casts
  cast_kernel<<<(MROWS * CDIM / 4 + 255) / 256, 256, 0, stream>>>(x, xb, MROWS * CDIM / 4);
  cast_kernel<<<(3 * CDIM * CDIM / 4 + 255) / 256, 256, 0, stream>>>(qkv_w, qw, 3 * CDIM * CDIM / 4);
  cast_kernel<<<(CDIM * CDIM / 4 + 255) / 256, 256, 0, stream>>>(proj_w, pw, CDIM * CDIM / 4);

  // combined mask+bias
  {
    int n = NWIN * NHEAD * NTOK * NTOK;
    build_comb<<<(n + 255) / 256, 256, 0, stream>>>(mask, bias_table, comb);
  }

  // qkv = x @ qkv_w^T + qkv_b, scattered to Q/K/V^T attention layouts
  gemm_bt<2><<<dim3((3 * CDIM) / 128, MROWS / 128), 256, 0, stream>>>(
      xb, qw, qkv_b, qb, vtb, MROWS, 3 * CDIM, CDIM);

  // attention (writes attn_out into xb region)
  attn_kernel<<<dim3(BW, NHEAD), 64, 0, stream>>>(qb, kb, vtb, comb, xb);

  // out = attn_out @ proj_w^T + proj_b (fp32, overwrites the V^T scratch)
  gemm_bt<0><<<dim3(CDIM / 128, MROWS / 128), 256, 0, stream>>>(
      xb, pw, proj_b, out, nullptr, MROWS, CDIM, CDIM);
}

// Round 3
// 758.557 us; speedup vs baseline: 1.0079x; 1.0079x over previous
//
#include <hip/hip_runtime.h>

// ---------------- types / helpers ----------------
typedef __attribute__((ext_vector_type(4))) float f32x4;
typedef __attribute__((ext_vector_type(8))) short s16x8;

#define MFMA16(a, b, c) __builtin_amdgcn_mfma_f32_16x16x32_bf16(a, b, c, 0, 0, 0)

static __device__ __forceinline__ unsigned short f2b(float f) {
  unsigned int u = __float_as_uint(f);
  u += 0x7fff + ((u >> 16) & 1);   // round-to-nearest-even
  return (unsigned short)(u >> 16);
}

static __device__ __forceinline__ void gload_lds16(const unsigned short* g, unsigned short* l) {
  __builtin_amdgcn_global_load_lds(
      (const __attribute__((address_space(1))) unsigned int*)g,
      (__attribute__((address_space(3))) unsigned int*)l, 16, 0, 0);
}

// ---------------- problem constants ----------------
#define BW    2048
#define NTOK  49
#define TPAD  64                 // padded tokens per window
#define CDIM  384
#define NHEAD 12
#define HDIM  32
#define NWIN  64
#define MROWS (BW * NTOK)        // 100352 (unpadded, for proj GEMM / final out)
#define MPAD  (BW * TPAD)        // 131072 (padded, for QKV GEMM)
#define SCALE 0.17677669529663687f  // 32^-0.5
#define QKP   ((size_t)BW * NHEAD * TPAD * HDIM)   // 50,331,648 elems per Q / K (padded)

// workspace byte offsets (total 310,545,408 B — under the round-1-proven 316.8 MB)
#define OFF_XP   ((size_t)0)            // x_pad bf16 [131072][384] (100,663,296); later attn_out bf16 (77 MB)
#define OFF_Q    ((size_t)100663296)    // Q [b][h][64][32] bf16 (100,663,296)
#define OFF_K    ((size_t)201326592)    // K [b][h][64][32] bf16 (100,663,296)
#define OFF_QW   ((size_t)301989888)    // qkv_w bf16 (884,736)
#define OFF_PW   ((size_t)302874624)    // proj_w bf16 (294,912)
#define OFF_COMB ((size_t)303169536)    // comb f32 (7,375,872)
// V^T [b][h][32][64] bf16 (100,663,296 B) lives in d_out (154 MB fp32, dead until proj GEMM).
// V^T pad cols t>=49 hold bias values; P columns >=49 are exactly 0 (exp2(-inf)) -> contribute 0.

// ---------------- cast fp32 -> bf16 with window padding 49 -> 64 rows ----------------
__global__ __launch_bounds__(256) void cast_pad(const float* __restrict__ x,
                                                unsigned short* __restrict__ xp) {
  const int i = blockIdx.x * 256 + threadIdx.x;   // chunk of 8 elems, 131072*48 chunks
  const int prow = i / 48;
  const int cc = i - prow * 48;
  const int t = prow & 63;
  s16x8 o;
  if (t < NTOK) {
    const int srow = (prow >> 6) * NTOK + t;
    const float4* s = (const float4*)(x + (size_t)srow * CDIM + cc * 8);
    float4 f0 = s[0], f1 = s[1];
    o[0] = f2b(f0.x); o[1] = f2b(f0.y); o[2] = f2b(f0.z); o[3] = f2b(f0.w);
    o[4] = f2b(f1.x); o[5] = f2b(f1.y); o[6] = f2b(f1.z); o[7] = f2b(f1.w);
  } else {
#pragma unroll
    for (int j = 0; j < 8; ++j) o[j] = 0;
  }
  *(s16x8*)(xp + (size_t)prow * CDIM + cc * 8) = o;
}

// ---------------- plain cast fp32 -> bf16 (x4) for weights ----------------
__global__ __launch_bounds__(256) void cast_kernel(const float* __restrict__ src,
                                                   unsigned short* __restrict__ dst, int n4) {
  int i = blockIdx.x * 256 + threadIdx.x;
  if (i >= n4) return;
  float4 f = ((const float4*)src)[i];
  ushort4 o;
  o.x = f2b(f.x); o.y = f2b(f.y); o.z = f2b(f.z); o.w = f2b(f.w);
  ((ushort4*)dst)[i] = o;
}

// ---------------- comb[w][h][i*49+j] = mask[w][ij] + bias_table[rel(i,j)][h] ----------------
__global__ __launch_bounds__(256) void build_comb(const float* __restrict__ mask,
                                                  const float* __restrict__ bias_table,
                                                  float* __restrict__ comb) {
  int idx = blockIdx.x * 256 + threadIdx.x;
  if (idx >= NWIN * NHEAD * NTOK * NTOK) return;
  int ij = idx % (NTOK * NTOK);
  int wh = idx / (NTOK * NTOK);
  int h = wh % NHEAD;
  int w = wh / NHEAD;
  int i = ij / NTOK, j = ij % NTOK;
  int yi = i / 7, xi = i % 7, yj = j / 7, xj = j % 7;
  int rel = (yi - yj + 6) * 13 + (xi - xj + 6);
  comb[idx] = mask[w * (NTOK * NTOK) + ij] + bias_table[rel * NHEAD + h];
}

// ---------------- m97-style GEMM: C = A[M,K] * Bt[N,K]^T + bias ----------------
// 128x128 tile, BK=32, 256 threads (4 waves, each 64x64), 16x16x32 bf16 MFMA.
// 1-D grid, M-tile fastest (A streams once/pass; B stays L2-resident; A re-reads hit L3).
// MODE 0: plain fp32 C[M,N] (proj).  MODE 2: padded-M qkv, LDS-staged epilogue scattering
// Q/K -> [b][h][64][32] bf16 and V -> V^T [b][h][32][64] bf16 with full-line 16 B stores.
#define CSTR 136   // epilogue LDS tile stride (elems): 16B-aligned rows, 68-word rows
template <int MODE, int MT>
__global__ __launch_bounds__(256) void gemm_bt(const unsigned short* __restrict__ A,
                                               const unsigned short* __restrict__ Bt,
                                               const float* __restrict__ bias,
                                               void* __restrict__ Cv,
                                               unsigned short* __restrict__ vtb,
                                               int N, int K) {
  __shared__ __align__(16) unsigned short smem[MODE == 2 ? 128 * CSTR : 8192];
  unsigned short* As = smem;
  unsigned short* Bs = smem + 4096;
  const int tid = threadIdx.x;
  const int lane = tid & 63;
  const int wave = tid >> 6;
  const int lr = lane & 15, lg = lane >> 4;
  const int wm = (wave >> 1) * 64, wn = (wave & 1) * 64;
  const int lin = blockIdx.x;
  const int tm = lin % MT;            // compile-time divisor -> magic mul
  const int tn = lin / MT;
  const size_t tileM = (size_t)tm * 128;
  const size_t tileN = (size_t)tn * 128;

  const unsigned short* Ab = A + tileM * K;
  const unsigned short* Bb = Bt + tileN * K;

  // staging: chunk c covers 8 bf16; row = c>>2, kcol = (c&3)*8; LDS dst lane-contiguous
  const int c0 = tid, c1 = tid + 256;
  const size_t a0 = (size_t)(c0 >> 2) * K + (c0 & 3) * 8;
  const size_t a1 = (size_t)(c1 >> 2) * K + (c1 & 3) * 8;

  f32x4 acc[4][4] = {};

  for (int k0 = 0; k0 < K; k0 += 32) {
    gload_lds16(Ab + a0 + k0, As + c0 * 8);
    gload_lds16(Ab + a1 + k0, As + c1 * 8);
    gload_lds16(Bb + a0 + k0, Bs + c0 * 8);
    gload_lds16(Bb + a1 + k0, Bs + c1 * 8);
    __syncthreads();
    s16x8 af[4], bf[4];
#pragma unroll
    for (int mt = 0; mt < 4; ++mt)
      af[mt] = *(const s16x8*)&As[(wm + mt * 16 + lr) * 32 + lg * 8];
#pragma unroll
    for (int nt = 0; nt < 4; ++nt)
      bf[nt] = *(const s16x8*)&Bs[(wn + nt * 16 + lr) * 32 + lg * 8];
#pragma unroll
    for (int mt = 0; mt < 4; ++mt)
#pragma unroll
      for (int nt = 0; nt < 4; ++nt)
        acc[mt][nt] = MFMA16(af[mt], bf[nt], acc[mt][nt]);
    __syncthreads();
  }

  if (MODE == 0) {
    float* Cf = (float*)Cv;
#pragma unroll
    for (int nt = 0; nt < 4; ++nt) {
      const size_t gcol = tileN + wn + nt * 16 + lr;
      const float bv = bias[gcol];
#pragma unroll
      for (int mt = 0; mt < 4; ++mt)
#pragma unroll
        for (int r = 0; r < 4; ++r) {
          const size_t grow = tileM + wm + mt * 16 + lg * 4 + r;  // C/D: row=(lane>>4)*4+r, col=lane&15
          Cf[grow * (size_t)N + gcol] = acc[mt][nt][r] + bv;
        }
    }
  } else {
    // ---- stage biased bf16 tile into LDS (overlays As/Bs; K-loop's final barrier protects) ----
    float bv[4];
#pragma unroll
    for (int nt = 0; nt < 4; ++nt) bv[nt] = bias[tileN + wn + nt * 16 + lr];
#pragma unroll
    for (int mt = 0; mt < 4; ++mt)
#pragma unroll
      for (int r = 0; r < 4; ++r) {
        const int row = wm + mt * 16 + lg * 4 + r;
#pragma unroll
        for (int nt = 0; nt < 4; ++nt)
          smem[row * CSTR + wn + nt * 16 + lr] = f2b(acc[mt][nt][r] + bv[nt]);
      }
    __syncthreads();

    const int which = tn / 3;          // 0=Q 1=K 2=V (block-uniform; tn in 0..8)
    if (which < 2) {
      unsigned short* qko = (unsigned short*)Cv + (size_t)which * QKP;
      // 2048 chunks of 16 B: row-major; full [bh][t][d] lines per instruction
#pragma unroll
      for (int i = 0; i < 8; ++i) {
        const int c = i * 256 + tid;
        const int row = c >> 4, cg = c & 15;
        s16x8 v = *(const s16x8*)&smem[row * CSTR + cg * 8];
        const int grow = (int)tileM + row;
        const int b = grow >> 6, t = grow & 63;
        const int col = (int)tileN + cg * 8 - which * CDIM;
        const int hh = col >> 5, d0 = col & 31;
        *(s16x8*)(qko + (((size_t)b * NHEAD + hh) * TPAD + t) * HDIM + d0) = v;
      }
    } else {
      // V^T: chunk = 8 consecutive t at fixed (window w, col); lanes 0..7 cover a full
      // 128 B line along t; LDS column reads are 8-way-banked (acceptable, once per block)
#pragma unroll
      for (int i = 0; i < 8; ++i) {
        const int c = i * 256 + tid;
        const int col = c >> 4, w = (c >> 3) & 1, tc = c & 7;
        s16x8 v;
#pragma unroll
        for (int j = 0; j < 8; ++j) v[j] = smem[(w * 64 + tc * 8 + j) * CSTR + col];
        const int b = tm * 2 + w;
        const int cc = (int)tileN + col - 2 * CDIM;
        const int hh = cc >> 5, d = cc & 31;
        *(s16x8*)(vtb + (((size_t)b * NHEAD + hh) * HDIM + d) * TPAD + tc * 8) = v;
      }
    }
  }
}

// ---------------- attention: one wave per (window b, head h) ----------------
// q,k: [b][h][64][32] bf16 (padded) ; vt: [b][h][32][64] bf16 ; comb: [64][12][49*49] f32
// out: [BW*49, 384] bf16 (unpadded). LDS: Pt only (9216 B).
#define PSTR 72   // Pt row stride (elems): 144 B rows, 16B-aligned
__global__ __launch_bounds__(64) void attn_kernel(const unsigned short* __restrict__ q,
                                                  const unsigned short* __restrict__ k,
                                                  const unsigned short* __restrict__ vt,
                                                  const float* __restrict__ comb,
                                                  unsigned short* __restrict__ out) {
  __shared__ __align__(16) unsigned short Pt[64 * PSTR];
  const int b = blockIdx.x;
  const int h = blockIdx.y;
  const int lane = threadIdx.x;
  const int lr = lane & 15, lg = lane >> 4;
  const size_t bh = (size_t)b * NHEAD + h;
  const unsigned short* qb = q + bh * (TPAD * HDIM);
  const unsigned short* kb = k + bh * (TPAD * HDIM);
  const unsigned short* vb = vt + bh * (HDIM * TPAD);

  // Q,K fragments, fully coalesced; all 64 padded rows are valid memory
  s16x8 qf[4], kf[4];
#pragma unroll
  for (int mt = 0; mt < 4; ++mt) {
    const int off = (mt * 16 + lr) * HDIM + lg * 8;
    qf[mt] = *(const s16x8*)(qb + off);
    kf[mt] = *(const s16x8*)(kb + off);
  }

  f32x4 S[4][4] = {};
#pragma unroll
  for (int mt = 0; mt < 4; ++mt)
#pragma unroll
    for (int nt = 0; nt < 4; ++nt)
      S[mt][nt] = MFMA16(qf[mt], kf[nt], S[mt][nt]);

  const float* cb = comb + ((size_t)(b & 63) * NHEAD + h) * (NTOK * NTOK);

  // masked softmax per row; a row lives across 16 lanes sharing lg, 4 regs (nt)
#pragma unroll
  for (int mt = 0; mt < 4; ++mt) {
#pragma unroll
    for (int r = 0; r < 4; ++r) {
      const int row = mt * 16 + lg * 4 + r;
      const bool rowok = row < NTOK;
      float sv[4];
      float mx = -1e30f;
#pragma unroll
      for (int nt = 0; nt < 4; ++nt) {
        const int col = nt * 16 + lr;
        float s;
        if (col < NTOK)
          s = rowok ? S[mt][nt][r] * SCALE + cb[row * NTOK + col] : 0.0f;
        else
          s = -1e30f;
        sv[nt] = s;
        mx = fmaxf(mx, s);
      }
#pragma unroll
      for (int off = 8; off; off >>= 1) mx = fmaxf(mx, __shfl_xor(mx, off, 16));
      float sum = 0.f;
#pragma unroll
      for (int nt = 0; nt < 4; ++nt) {
        float e = exp2f((sv[nt] - mx) * 1.4426950408889634f);  // col>=49 -> exp2(-inf) = 0 exactly
        sv[nt] = e;
        sum += e;
      }
#pragma unroll
      for (int off = 8; off; off >>= 1) sum += __shfl_xor(sum, off, 16);
      const float inv = 1.0f / sum;
#pragma unroll
      for (int nt = 0; nt < 4; ++nt)
        Pt[row * PSTR + nt * 16 + lr] = f2b(sv[nt] * inv);
    }
  }
  __syncthreads();

  // O = P(64x64, cols>=49 are 0) * V^T-frags from global (pad cols multiply by exact 0)
  f32x4 O[4][2] = {};
#pragma unroll
  for (int ks = 0; ks < 2; ++ks) {
    s16x8 pf[4], vf[2];
#pragma unroll
    for (int mt = 0; mt < 4; ++mt)
      pf[mt] = *(const s16x8*)&Pt[(mt * 16 + lr) * PSTR + ks * 32 + lg * 8];
#pragma unroll
    for (int n2 = 0; n2 < 2; ++n2)
      vf[n2] = *(const s16x8*)(vb + (n2 * 16 + lr) * TPAD + ks * 32 + lg * 8);
#pragma unroll
    for (int mt = 0; mt < 4; ++mt)
#pragma unroll
      for (int n2 = 0; n2 < 2; ++n2)
        O[mt][n2] = MFMA16(pf[mt], vf[n2], O[mt][n2]);
  }

  unsigned short* ob = out + (size_t)b * NTOK * CDIM + h * HDIM;
#pragma unroll
  for (int mt = 0; mt < 4; ++mt)
#pragma unroll
    for (int r = 0; r < 4; ++r) {
      const int row = mt * 16 + lg * 4 + r;
      if (row < NTOK) {
#pragma unroll
        for (int n2 = 0; n2 < 2; ++n2)
          ob[(size_t)row * CDIM + n2 * 16 + lr] = f2b(O[mt][n2][r]);
      }
    }
}

// ---------------- launch ----------------
extern "C" void kernel_launch(void* const* d_in, const int* in_sizes, int n_in,
                              void* d_out, int out_size, void* d_ws, size_t ws_size,
                              hipStream_t stream) {
  const float* x          = (const float*)d_in[0];
  const float* mask       = (const float*)d_in[1];
  const float* qkv_w      = (const float*)d_in[2];
  const float* qkv_b      = (const float*)d_in[3];
  const float* proj_w     = (const float*)d_in[4];
  const float* proj_b     = (const float*)d_in[5];
  const float* bias_table = (const float*)d_in[6];
  float* out = (float*)d_out;
  char* ws = (char*)d_ws;

  unsigned short* xp   = (unsigned short*)(ws + OFF_XP);   // x_pad bf16, later attn_out
  unsigned short* qb   = (unsigned short*)(ws + OFF_Q);
  unsigned short* kb   = (unsigned short*)(ws + OFF_K);
  unsigned short* qw   = (unsigned short*)(ws + OFF_QW);
  unsigned short* pw   = (unsigned short*)(ws + OFF_PW);
  float* comb          = (float*)(ws + OFF_COMB);
  unsigned short* vtb  = (unsigned short*)d_out;           // V^T scratch in d_out (dead until proj)

  // padded x cast + weight casts
  cast_pad<<<(MPAD * 48) / 256, 256, 0, stream>>>(x, xp);
  cast_kernel<<<(3 * CDIM * CDIM / 4 + 255) / 256, 256, 0, stream>>>(qkv_w, qw, 3 * CDIM * CDIM / 4);
  cast_kernel<<<(CDIM * CDIM / 4 + 255) / 256, 256, 0, stream>>>(proj_w, pw, CDIM * CDIM / 4);

  // combined mask+bias
  {
    int n = NWIN * NHEAD * NTOK * NTOK;
    build_comb<<<(n + 255) / 256, 256, 0, stream>>>(mask, bias_table, comb);
  }

  // qkv = x_pad @ qkv_w^T + qkv_b, scattered to padded Q/K/V^T attention layouts
  gemm_bt<2, MPAD / 128><<<(MPAD / 128) * (3 * CDIM / 128), 256, 0, stream>>>(
      xp, qw, qkv_b, qb, vtb, 3 * CDIM, CDIM);

  // attention (writes unpadded attn_out into xp region)
  attn_kernel<<<dim3(BW, NHEAD), 64, 0, stream>>>(qb, kb, vtb, comb, xp);

  // out = attn_out @ proj_w^T + proj_b (fp32, overwrites the V^T scratch)
  gemm_bt<0, MROWS / 128><<<(MROWS / 128) * (CDIM / 128), 256, 0, stream>>>(
      xp, pw, proj_b, out, nullptr, CDIM, CDIM);
}

// Round 4
// 652.697 us; speedup vs baseline: 1.1713x; 1.1622x over previous
//
#include <hip/hip_runtime.h>

// ---------------- types / helpers ----------------
typedef __attribute__((ext_vector_type(4))) float f32x4;
typedef __attribute__((ext_vector_type(8))) short s16x8;
typedef __attribute__((ext_vector_type(2))) unsigned int u32x2;

#define MFMA16(a, b, c) __builtin_amdgcn_mfma_f32_16x16x32_bf16(a, b, c, 0, 0, 0)

static __device__ __forceinline__ unsigned short f2b(float f) {
  unsigned int u = __float_as_uint(f);
  u += 0x7fff + ((u >> 16) & 1);   // round-to-nearest-even
  return (unsigned short)(u >> 16);
}
static __device__ __forceinline__ unsigned int pack2(float a, float b) {
  return (unsigned int)f2b(a) | ((unsigned int)f2b(b) << 16);
}

static __device__ __forceinline__ void gload_lds16(const unsigned short* g, unsigned short* l) {
  __builtin_amdgcn_global_load_lds(
      (const __attribute__((address_space(1))) unsigned int*)g,
      (__attribute__((address_space(3))) unsigned int*)l, 16, 0, 0);
}

// ---------------- problem constants ----------------
#define BW    2048
#define NTOK  49
#define TPAD  64                 // padded tokens per window
#define CDIM  384
#define NHEAD 12
#define HDIM  32
#define NWIN  64
#define MROWS (BW * NTOK)        // 100352 (unpadded, proj GEMM / final out)
#define MPAD  (BW * TPAD)        // 131072 (padded, QKV GEMM)
#define SCALE 0.17677669529663687f  // 32^-0.5 (folded into Q at QKV epilogue)
#define QKP   ((size_t)BW * NHEAD * TPAD * HDIM)   // elems per Q / K (padded)

// workspace byte offsets (total 310,545,408 B)
#define OFF_XP   ((size_t)0)            // x_pad bf16 [131072][384]; later attn_out bf16
#define OFF_Q    ((size_t)100663296)    // Q [b][h][64][32] bf16 (pre-scaled by SCALE)
#define OFF_K    ((size_t)201326592)    // K [b][h][64][32] bf16
#define OFF_QW   ((size_t)301989888)    // qkv_w bf16
#define OFF_PW   ((size_t)302874624)    // proj_w bf16
#define OFF_COMB ((size_t)303169536)    // comb f32
// V^T [b][h][32][64] bf16 lives in d_out (dead until proj GEMM overwrites it).

// ---------------- cast fp32 -> bf16 with window padding 49 -> 64 rows ----------------
__global__ __launch_bounds__(256) void cast_pad(const float* __restrict__ x,
                                                unsigned short* __restrict__ xp) {
  const int i = blockIdx.x * 256 + threadIdx.x;   // chunk of 8 elems
  const int prow = i / 48;
  const int cc = i - prow * 48;
  const int t = prow & 63;
  s16x8 o;
  if (t < NTOK) {
    const int srow = (prow >> 6) * NTOK + t;
    const float4* s = (const float4*)(x + (size_t)srow * CDIM + cc * 8);
    float4 f0 = s[0], f1 = s[1];
    o[0] = f2b(f0.x); o[1] = f2b(f0.y); o[2] = f2b(f0.z); o[3] = f2b(f0.w);
    o[4] = f2b(f1.x); o[5] = f2b(f1.y); o[6] = f2b(f1.z); o[7] = f2b(f1.w);
  } else {
#pragma unroll
    for (int j = 0; j < 8; ++j) o[j] = 0;
  }
  *(s16x8*)(xp + (size_t)prow * CDIM + cc * 8) = o;
}

// ---------------- plain cast fp32 -> bf16 (x4) for weights ----------------
__global__ __launch_bounds__(256) void cast_kernel(const float* __restrict__ src,
                                                   unsigned short* __restrict__ dst, int n4) {
  int i = blockIdx.x * 256 + threadIdx.x;
  if (i >= n4) return;
  float4 f = ((const float4*)src)[i];
  ushort4 o;
  o.x = f2b(f.x); o.y = f2b(f.y); o.z = f2b(f.z); o.w = f2b(f.w);
  ((ushort4*)dst)[i] = o;
}

// ---------------- comb[w][h][i*49+j] = mask[w][ij] + bias_table[rel(i,j)][h] ----------------
__global__ __launch_bounds__(256) void build_comb(const float* __restrict__ mask,
                                                  const float* __restrict__ bias_table,
                                                  float* __restrict__ comb) {
  int idx = blockIdx.x * 256 + threadIdx.x;
  if (idx >= NWIN * NHEAD * NTOK * NTOK) return;
  int ij = idx % (NTOK * NTOK);
  int wh = idx / (NTOK * NTOK);
  int h = wh % NHEAD;
  int w = wh / NHEAD;
  int i = ij / NTOK, j = ij % NTOK;
  int yi = i / 7, xi = i % 7, yj = j / 7, xj = j % 7;
  int rel = (yi - yj + 6) * 13 + (xi - xj + 6);
  comb[idx] = mask[w * (NTOK * NTOK) + ij] + bias_table[rel * NHEAD + h];
}

// ---------------- GEMM: C = A[M,K] * Bt[N,K]^T + bias ----------------
// 128x128 tile, BK=32, 256 threads (4 waves, 64x64 each), 16x16x32 bf16 MFMA.
// Supertile grid: SC M-tiles per chunk, N-fastest within chunk (A-chunk stays L2/L3-hot).
// MODE 0: plain fp32 C[M,N] (proj).
// MODE 2: padded-M qkv. Q/K tiles compute D^T (operand swap) so each lane holds 4
// consecutive output cols -> b64 LDS staging; V tiles stay normal (4 consecutive t)
// staged into a [d][t] image. Readback does full-line 16 B coalesced stores (no RFO).
#define CSTR 136   // epilogue LDS image stride (elems)
template <int MODE, int MT, int SC, int NT>
__global__ __launch_bounds__(256) void gemm_bt(const unsigned short* __restrict__ A,
                                               const unsigned short* __restrict__ Bt,
                                               const float* __restrict__ bias,
                                               void* __restrict__ Cv,
                                               unsigned short* __restrict__ vtb,
                                               int N, int K) {
  __shared__ __align__(16) unsigned short smem[MODE == 2 ? 128 * CSTR : 8192];
  unsigned short* As = smem;
  unsigned short* Bs = smem + 4096;
  const int tid = threadIdx.x;
  const int lane = tid & 63;
  const int wave = tid >> 6;
  const int lr = lane & 15, lg = lane >> 4;
  const int wm = (wave >> 1) * 64, wn = (wave & 1) * 64;

  // supertile decomposition (all compile-time divisors)
  const int lin = blockIdx.x;
  const int chunk = lin / (SC * NT);
  const int rmd = lin - chunk * (SC * NT);
  const int tn = rmd / SC;
  const int tm = chunk * SC + (rmd - tn * SC);
  const size_t tileM = (size_t)tm * 128;
  const size_t tileN = (size_t)tn * 128;

  const unsigned short* Ab = A + tileM * K;
  const unsigned short* Bb = Bt + tileN * K;

  // staging: chunk c covers 8 bf16; row = c>>2, kcol = (c&3)*8; LDS dst lane-contiguous
  const int c0 = tid, c1 = tid + 256;
  const size_t a0 = (size_t)(c0 >> 2) * K + (c0 & 3) * 8;
  const size_t a1 = (size_t)(c1 >> 2) * K + (c1 & 3) * 8;

  // operand roles: swap for Q/K tiles so D rows = N-dir (4 consecutive cols per lane)
  const bool swp = (MODE == 2) && (tn < 6);
  const unsigned short* srcA = swp ? Bs : As;
  const unsigned short* srcB = swp ? As : Bs;
  const int rbA = swp ? wn : wm;   // first-operand base  (D rows)
  const int rbB = swp ? wm : wn;   // second-operand base (D cols)

  f32x4 acc[4][4] = {};

  for (int k0 = 0; k0 < K; k0 += 32) {
    gload_lds16(Ab + a0 + k0, As + c0 * 8);
    gload_lds16(Ab + a1 + k0, As + c1 * 8);
    gload_lds16(Bb + a0 + k0, Bs + c0 * 8);
    gload_lds16(Bb + a1 + k0, Bs + c1 * 8);
    __syncthreads();
    s16x8 af[4], bf[4];
#pragma unroll
    for (int i = 0; i < 4; ++i)
      af[i] = *(const s16x8*)&srcA[(rbA + i * 16 + lr) * 32 + lg * 8];
#pragma unroll
    for (int j = 0; j < 4; ++j)
      bf[j] = *(const s16x8*)&srcB[(rbB + j * 16 + lr) * 32 + lg * 8];
#pragma unroll
    for (int i = 0; i < 4; ++i)
#pragma unroll
      for (int j = 0; j < 4; ++j)
        acc[i][j] = MFMA16(af[i], bf[j], acc[i][j]);
    __syncthreads();
  }

  if (MODE == 0) {
    // D rows = M (i, lg*4+r), cols = N (j, lr); quarter-wave writes 64 B lines
    float* Cf = (float*)Cv;
#pragma unroll
    for (int j = 0; j < 4; ++j) {
      const size_t gcol = tileN + wn + j * 16 + lr;
      const float bv = bias[gcol];
#pragma unroll
      for (int i = 0; i < 4; ++i)
#pragma unroll
        for (int r = 0; r < 4; ++r) {
          const size_t grow = tileM + wm + i * 16 + lg * 4 + r;
          Cf[grow * (size_t)N + gcol] = acc[i][j][r] + bv;
        }
    }
  } else {
    // ---- stage biased bf16 tile into LDS image, packed b64 writes ----
    // image row = rbB + 16j + lr (Q/K: t-dir; V: d-dir), col = rbA + 16i + lg*4 (+r)
    const float scl = (tn < 3) ? SCALE : 1.0f;   // fold attention scale into Q
    float4 bb[4];
    if (swp) {
#pragma unroll
      for (int i = 0; i < 4; ++i)
        bb[i] = *(const float4*)&bias[tileN + rbA + i * 16 + lg * 4];
    }
#pragma unroll
    for (int j = 0; j < 4; ++j) {
      const int irow = rbB + j * 16 + lr;
      const float bvr = swp ? 0.0f : bias[tileN + irow];
#pragma unroll
      for (int i = 0; i < 4; ++i) {
        const int icol = rbA + i * 16 + lg * 4;
        float v0, v1, v2, v3;
        if (swp) {
          v0 = (acc[i][j][0] + bb[i].x) * scl;
          v1 = (acc[i][j][1] + bb[i].y) * scl;
          v2 = (acc[i][j][2] + bb[i].z) * scl;
          v3 = (acc[i][j][3] + bb[i].w) * scl;
        } else {
          v0 = acc[i][j][0] + bvr; v1 = acc[i][j][1] + bvr;
          v2 = acc[i][j][2] + bvr; v3 = acc[i][j][3] + bvr;
        }
        u32x2 pk; pk[0] = pack2(v0, v1); pk[1] = pack2(v2, v3);
        *(u32x2*)&smem[irow * CSTR + icol] = pk;
      }
    }
    __syncthreads();

    // ---- readback: 2048 16 B chunks, full-line coalesced global stores ----
    const int which = tn / 3;          // 0=Q 1=K 2=V (block-uniform)
    if (which < 2) {
      unsigned short* dst = (unsigned short*)Cv + (size_t)which * QKP;
#pragma unroll
      for (int i8 = 0; i8 < 8; ++i8) {
        const int c = i8 * 256 + tid;
        const int row = c >> 4, cg = c & 15;            // row = t-dir, cg = d-chunk
        s16x8 v = *(const s16x8*)&smem[row * CSTR + cg * 8];
        const int b = (int)(tileM >> 6) + (row >> 6);
        const int t = row & 63;
        const int cc = (int)tileN - which * CDIM + cg * 8;
        const int hh = cc >> 5, d0 = cc & 31;
        *(s16x8*)(dst + (((size_t)b * NHEAD + hh) * TPAD + t) * HDIM + d0) = v;
      }
    } else {
#pragma unroll
      for (int i8 = 0; i8 < 8; ++i8) {
        const int c = i8 * 256 + tid;
        const int row = c >> 4, cg = c & 15;            // row = d-dir, cg = t-chunk
        s16x8 v = *(const s16x8*)&smem[row * CSTR + cg * 8];
        const int cc = (int)tileN - 2 * CDIM + row;
        const int hh = cc >> 5, d = cc & 31;
        const int w = cg >> 3, t0 = (cg & 7) * 8;
        const int b = (int)(tileM >> 6) + w;
        *(s16x8*)(vtb + (((size_t)b * NHEAD + hh) * HDIM + d) * TPAD + t0) = v;
      }
    }
  }
}

// ---------------- attention: 256-thr block = 4 waves, one (window b, head h) per wave ----
// q (pre-scaled), k: [b][h][64][32] bf16 ; vt: [b][h][32][64] bf16 ; comb f32
// out: [BW*49, 384] bf16. Wave-private Pt (49 rows) -> no barriers; 30384 B/block
// -> 5 blocks x 4 waves = 20 waves/CU.
#define PSTR 72
__global__ __launch_bounds__(256) void attn_kernel(const unsigned short* __restrict__ q,
                                                   const unsigned short* __restrict__ k,
                                                   const unsigned short* __restrict__ vt,
                                                   const float* __restrict__ comb,
                                                   unsigned short* __restrict__ out) {
  // 3 full wave buffers (49*72) + tail so wave 3's over-reads (rows<64) stay in-bounds
  __shared__ __align__(16) unsigned short PtAll[3 * NTOK * PSTR + TPAD * PSTR];
  const int wave = threadIdx.x >> 6;
  const int lane = threadIdx.x & 63;
  const int b = blockIdx.x;
  const int h = blockIdx.y * 4 + wave;
  unsigned short* Pt = PtAll + wave * (NTOK * PSTR);
  const int lr = lane & 15, lg = lane >> 4;
  const size_t bh = (size_t)b * NHEAD + h;
  const unsigned short* qb = q + bh * (TPAD * HDIM);
  const unsigned short* kb = k + bh * (TPAD * HDIM);
  const unsigned short* vb = vt + bh * (HDIM * TPAD);

  // Q,K fragments, fully coalesced; all 64 padded rows are valid memory
  s16x8 qf[4], kf[4];
#pragma unroll
  for (int mt = 0; mt < 4; ++mt) {
    const int off = (mt * 16 + lr) * HDIM + lg * 8;
    qf[mt] = *(const s16x8*)(qb + off);
    kf[mt] = *(const s16x8*)(kb + off);
  }

  f32x4 S[4][4] = {};
#pragma unroll
  for (int mt = 0; mt < 4; ++mt)
#pragma unroll
    for (int nt = 0; nt < 4; ++nt)
      S[mt][nt] = MFMA16(qf[mt], kf[nt], S[mt][nt]);

  const float* cb = comb + ((size_t)(b & 63) * NHEAD + h) * (NTOK * NTOK);

  // masked softmax per row (Q pre-scaled, so no SCALE here)
#pragma unroll
  for (int mt = 0; mt < 4; ++mt) {
#pragma unroll
    for (int r = 0; r < 4; ++r) {
      const int row = mt * 16 + lg * 4 + r;
      const bool rowok = row < NTOK;
      float sv[4];
      float mx = -1e30f;
#pragma unroll
      for (int nt = 0; nt < 4; ++nt) {
        const int col = nt * 16 + lr;
        float s;
        if (col < NTOK)
          s = rowok ? S[mt][nt][r] + cb[row * NTOK + col] : 0.0f;
        else
          s = -1e30f;
        sv[nt] = s;
        mx = fmaxf(mx, s);
      }
#pragma unroll
      for (int off = 8; off; off >>= 1) mx = fmaxf(mx, __shfl_xor(mx, off, 16));
      float sum = 0.f;
#pragma unroll
      for (int nt = 0; nt < 4; ++nt) {
        float e = exp2f((sv[nt] - mx) * 1.4426950408889634f);  // col>=49 -> exactly 0
        sv[nt] = e;
        sum += e;
      }
#pragma unroll
      for (int off = 8; off; off >>= 1) sum += __shfl_xor(sum, off, 16);
      const float inv = 1.0f / sum;
      if (rowok) {
#pragma unroll
        for (int nt = 0; nt < 4; ++nt)
          Pt[row * PSTR + nt * 16 + lr] = f2b(sv[nt] * inv);
      }
    }
  }
  // no barrier: Pt is wave-private; compiler orders ds ops via lgkmcnt.
  // PV reads rows 49..63 -> neighbor-wave garbage feeding only discarded O rows.

  f32x4 O[4][2] = {};
#pragma unroll
  for (int ks = 0; ks < 2; ++ks) {
    s16x8 pf[4], vf[2];
#pragma unroll
    for (int mt = 0; mt < 4; ++mt)
      pf[mt] = *(const s16x8*)&Pt[(mt * 16 + lr) * PSTR + ks * 32 + lg * 8];
#pragma unroll
    for (int n2 = 0; n2 < 2; ++n2)
      vf[n2] = *(const s16x8*)(vb + (n2 * 16 + lr) * TPAD + ks * 32 + lg * 8);
#pragma unroll
    for (int mt = 0; mt < 4; ++mt)
#pragma unroll
      for (int n2 = 0; n2 < 2; ++n2)
        O[mt][n2] = MFMA16(pf[mt], vf[n2], O[mt][n2]);
  }

  unsigned short* ob = out + (size_t)b * NTOK * CDIM + h * HDIM;
#pragma unroll
  for (int mt = 0; mt < 4; ++mt)
#pragma unroll
    for (int r = 0; r < 4; ++r) {
      const int row = mt * 16 + lg * 4 + r;
      if (row < NTOK) {
#pragma unroll
        for (int n2 = 0; n2 < 2; ++n2)
          ob[(size_t)row * CDIM + n2 * 16 + lr] = f2b(O[mt][n2][r]);
      }
    }
}

// ---------------- launch ----------------
extern "C" void kernel_launch(void* const* d_in, const int* in_sizes, int n_in,
                              void* d_out, int out_size, void* d_ws, size_t ws_size,
                              hipStream_t stream) {
  const float* x          = (const float*)d_in[0];
  const float* mask       = (const float*)d_in[1];
  const float* qkv_w      = (const float*)d_in[2];
  const float* qkv_b      = (const float*)d_in[3];
  const float* proj_w     = (const float*)d_in[4];
  const float* proj_b     = (const float*)d_in[5];
  const float* bias_table = (const float*)d_in[6];
  float* out = (float*)d_out;
  char* ws = (char*)d_ws;

  unsigned short* xp   = (unsigned short*)(ws + OFF_XP);   // x_pad bf16, later attn_out
  unsigned short* qb   = (unsigned short*)(ws + OFF_Q);
  unsigned short* kb   = (unsigned short*)(ws + OFF_K);
  unsigned short* qw   = (unsigned short*)(ws + OFF_QW);
  unsigned short* pw   = (unsigned short*)(ws + OFF_PW);
  float* comb          = (float*)(ws + OFF_COMB);
  unsigned short* vtb  = (unsigned short*)d_out;           // V^T scratch in d_out

  cast_pad<<<(MPAD * 48) / 256, 256, 0, stream>>>(x, xp);
  cast_kernel<<<(3 * CDIM * CDIM / 4 + 255) / 256, 256, 0, stream>>>(qkv_w, qw, 3 * CDIM * CDIM / 4);
  cast_kernel<<<(CDIM * CDIM / 4 + 255) / 256, 256, 0, stream>>>(proj_w, pw, CDIM * CDIM / 4);

  {
    int n = NWIN * NHEAD * NTOK * NTOK;
    build_comb<<<(n + 255) / 256, 256, 0, stream>>>(mask, bias_table, comb);
  }

  // qkv = x_pad @ qkv_w^T + qkv_b -> padded Q (pre-scaled) / K / V^T layouts
  // grid: 16 chunks x (9 N-tiles x 64 M-tiles)
  gemm_bt<2, MPAD / 128, 64, 9><<<(MPAD / 128) * 9, 256, 0, stream>>>(
      xp, qw, qkv_b, qb, vtb, 3 * CDIM, CDIM);

  // attention: 4 heads per block (one per wave)
  attn_kernel<<<dim3(BW, NHEAD / 4), 256, 0, stream>>>(qb, kb, vtb, comb, xp);

  // out = attn_out @ proj_w^T + proj_b (fp32, overwrites V^T scratch)
  gemm_bt<0, MROWS / 128, 49, 3><<<(MROWS / 128) * 3, 256, 0, stream>>>(
      xp, pw, proj_b, out, nullptr, CDIM, CDIM);
}